// Round 1
// baseline (3162.838 us; speedup 1.0000x reference)
//
#include <hip/hip_runtime.h>

// FlexibleScanpathHistoryEncoding: fused masked grouped conv -> dense 64->128 3x3 conv
// out[b,o,p] = sum_{c,kh,kw} xmask[b,c,p+kh,p+kw] * W[f(c),o,j(c),kh,kw] + sum_f valid[b,f]*bias[f,o]
//   with c = j*4+f, xmask = valid[b,c&3] ? nan_to_num(x) : 0
//
// Round 0: fp32 register-tiled direct conv (compute-bound baseline, ~157 TF fp32 ceiling).

#define B_    32
#define CIN   64
#define HH    192
#define WW    192
#define OUTC  128
#define HO    190
#define WO    190

#define OC_T  64   // out-channel tile per block (2 tiles cover 128)
#define OH_T  4    // output rows per block
#define OW_T  32   // output cols per block
#define CC    16   // input-channel chunk staged in LDS

__global__ __launch_bounds__(256) void fse_conv_fp32(
    const float* __restrict__ x,
    const float* __restrict__ w,
    const float* __restrict__ bias,
    float* __restrict__ out)
{
    // input tile: CC channels x 6 rows x 34 cols (padded to 36)
    __shared__ float xs[CC][6][36];          // 13824 B
    // weights: CC channels x 9 taps x 64 oc (oc contiguous -> b128 broadcast reads)
    __shared__ float wsm[CC][9][64];         // 36864 B

    const int tw  = blockIdx.x;              // 0..5   (ow tiles)
    const int th  = blockIdx.y;              // 0..47  (oh tiles)
    const int bz  = blockIdx.z;              // 0..63  (b * 2 + oc_tile)
    const int b   = bz >> 1;
    const int ocb = (bz & 1) * OC_T;
    const int ow0 = tw * OW_T;
    const int oh0 = th * OH_T;
    const int t    = (int)threadIdx.x;
    const int lane = t & 31;                 // ow offset within tile
    const int og   = t >> 5;                 // oc group (8 oc each)

    const size_t xbase = (size_t)b * CIN * HH * WW;

    // fixation validity from marker channels tensor[b, f, 0, 0], f = 0..3
    float vmask[4];
#pragma unroll
    for (int f = 0; f < 4; ++f) {
        float m = x[xbase + (size_t)f * (HH * WW)];
        vmask[f] = (m == m) ? 1.0f : 0.0f;   // !isnan
    }

    float acc[4][8];
#pragma unroll
    for (int r = 0; r < 4; ++r)
#pragma unroll
        for (int i = 0; i < 8; ++i) acc[r][i] = 0.0f;

    for (int c0 = 0; c0 < CIN; c0 += CC) {
        // ---- stage input chunk: coalesced along cols ----
        for (int idx = t; idx < CC * 6 * 36; idx += 256) {
            int c   = idx / (6 * 36);
            int rem = idx - c * (6 * 36);
            int r   = rem / 36;
            int col = rem - r * 36;
            float v = 0.0f;
            int gh = oh0 + r;
            int gw = ow0 + col;
            if (col < 34 && gh < HH && gw < WW) {
                v = x[xbase + (size_t)(c0 + c) * (HH * WW) + gh * WW + gw];
                v = (v == v) ? v : 0.0f;       // nan_to_num
                v *= vmask[(c0 + c) & 3];      // fixation mask (c = j*4+f -> f = c&3)
            }
            xs[c][r][col] = v;
        }
        // ---- stage weight chunk: wsm[c][k][oc] = weight[f][ocb+oc][j][kh][kw] ----
        for (int idx = t; idx < CC * 9 * 64; idx += 256) {
            int cl  = idx / 576;
            int rem = idx - cl * 576;
            int oc  = rem / 9;
            int k   = rem - oc * 9;
            int cg  = c0 + cl;
            int f = cg & 3;
            int j = cg >> 2;
            wsm[cl][k][oc] = w[(((size_t)(f * OUTC + ocb + oc)) * 16 + j) * 9 + k];
        }
        __syncthreads();

        // ---- compute: 32 FMA per (c, tap) step ----
        for (int c = 0; c < CC; ++c) {
            float xv[6][3];
#pragma unroll
            for (int rr = 0; rr < 6; ++rr)
#pragma unroll
                for (int kw = 0; kw < 3; ++kw)
                    xv[rr][kw] = xs[c][rr][lane + kw];
#pragma unroll
            for (int kh = 0; kh < 3; ++kh) {
#pragma unroll
                for (int kw = 0; kw < 3; ++kw) {
                    const float4* wp = (const float4*)&wsm[c][kh * 3 + kw][og * 8];
                    float4 wa = wp[0];
                    float4 wb = wp[1];
                    float wv[8] = {wa.x, wa.y, wa.z, wa.w, wb.x, wb.y, wb.z, wb.w};
#pragma unroll
                    for (int r = 0; r < 4; ++r) {
                        float xvv = xv[r + kh][kw];
#pragma unroll
                        for (int i = 0; i < 8; ++i)
                            acc[r][i] = fmaf(xvv, wv[i], acc[r][i]);
                    }
                }
            }
        }
        __syncthreads();
    }

    // ---- epilogue: masked bias + store ----
    float bs[8];
#pragma unroll
    for (int i = 0; i < 8; ++i) {
        int oc = ocb + og * 8 + i;
        float s = 0.0f;
#pragma unroll
        for (int f = 0; f < 4; ++f) s += vmask[f] * bias[f * OUTC + oc];
        bs[i] = s;
    }

    const int ow = ow0 + lane;
    if (ow < WO) {
#pragma unroll
        for (int r = 0; r < 4; ++r) {
            int oh = oh0 + r;
            if (oh < HO) {
#pragma unroll
                for (int i = 0; i < 8; ++i) {
                    int oc = ocb + og * 8 + i;
                    out[((size_t)b * OUTC + oc) * (HO * WO) + oh * WO + ow] = acc[r][i] + bs[i];
                }
            }
        }
    }
}

extern "C" void kernel_launch(void* const* d_in, const int* in_sizes, int n_in,
                              void* d_out, int out_size, void* d_ws, size_t ws_size,
                              hipStream_t stream) {
    const float* x    = (const float*)d_in[0];   // [32, 64, 192, 192]
    const float* w    = (const float*)d_in[1];   // [4, 128, 16, 3, 3]
    const float* bias = (const float*)d_in[2];   // [4, 128]
    float* out = (float*)d_out;                  // [32, 128, 190, 190]

    dim3 grid(6, 48, 64);   // ow tiles, oh tiles, b*2 + oc_tile
    fse_conv_fp32<<<grid, 256, 0, stream>>>(x, w, bias, out);
}